// Round 14
// baseline (663.306 us; speedup 1.0000x reference)
//
#include <hip/hip_runtime.h>
#include <hip/hip_bf16.h>

#define N_NODES 100000
#define N_EDGES 1200000
#define N_GRAPH 1000
#define F_INN   7
#define HDIM    64
#define GFEAT   10
#define T_OUT   5
#define EPSF    1e-5f
#define NBLK_SCAN ((N_NODES + 255) / 256)   // 391

// flags: [0]=edge wide(int64) [1]=batch wide [2]=1D fp32 [3]=world fp32

__device__ __forceinline__ float ldf(const void* p, int i, int isf32) {
    return isf32 ? ((const float*)p)[i]
                 : __bfloat162float(((const __hip_bfloat16*)p)[i]);
}
__device__ __forceinline__ float b2f(__hip_bfloat16 v) { return __bfloat162float(v); }
__device__ __forceinline__ float u_lo(unsigned u) { return __uint_as_float(u << 16); }
__device__ __forceinline__ float u_hi(unsigned u) { return __uint_as_float(u & 0xFFFF0000u); }
__device__ __forceinline__ int ld_src(const int* edge, int e, int wide) {
    return wide ? edge[2 * e] : edge[e];
}
__device__ __forceinline__ int ld_dst(const int* edge, int e, int wide) {
    return wide ? edge[2 * (N_EDGES + e)] : edge[N_EDGES + e];
}
__device__ __forceinline__ int ld_batch(const int* batch, int v, int wide) {
    return wide ? batch[2 * v] : batch[v];
}

__global__ void SimpleGCN_6640019440134_kernel() {}

__global__ void s14_fill(float* out, int n, float val) {
    int i = blockIdx.x * blockDim.x + threadIdx.x;
    if (i < n) out[i] = val;
}

__global__ void __launch_bounds__(256) s14_probe(const int* edge, const int* batch,
                                                 const unsigned* g1,
                                                 const unsigned short* x,
                                                 const unsigned short* W1,
                                                 const unsigned short* W2,
                                                 int* flags) {
    __shared__ int sh[8];
    int t = threadIdx.x;
    if (t < 8) sh[t] = 0;
    __syncthreads();
    { int pos = 1 + 2 * 4687 * t; if (edge[pos] != 0) atomicOr(&sh[0], 1); }
    { int pos = (N_NODES - 511) + 2 * t; if (batch[pos] != 0) atomicOr(&sh[1], 1); }
    if (t < 16 && g1[t] != 0x3F800000u) atomicOr(&sh[2], 1);
    {
        int e = (x[t] >> 7) & 0xFF;  if (e >= 100 && e <= 140) atomicAdd(&sh[3], 1);
        e = (W1[t] >> 7) & 0xFF;     if (e >= 100 && e <= 140) atomicAdd(&sh[4], 1);
        e = (W2[t] >> 7) & 0xFF;     if (e >= 100 && e <= 140) atomicAdd(&sh[5], 1);
    }
    __syncthreads();
    if (t == 0) {
        flags[0] = (sh[0] == 0);
        flags[1] = (sh[1] == 0);
        flags[2] = (sh[2] == 0);
        int fx = (sh[3] < 192), fw1 = (sh[4] < 192), fw2 = (sh[5] < 192);
        flags[3] = (fx + fw1 + fw2 >= 2);
    }
}

__global__ void s14_zero(int* zbuf, int zcount) {
    int i = blockIdx.x * blockDim.x + threadIdx.x;
    if (i < zcount) zbuf[i] = 0;
}

__global__ void s14_deg(const int* __restrict__ edge, int* degi, const int* __restrict__ fl) {
    int wide = fl[0];
    int e = blockIdx.x * blockDim.x + threadIdx.x;
    if (e < N_EDGES) {
        unsigned d = (unsigned)ld_dst(edge, e, wide);
        if (d < N_NODES) atomicAdd(&degi[d], 1);
    }
}

__global__ void __launch_bounds__(256) s14_scan1(const int* __restrict__ degi,
                                                 int* __restrict__ cursor, int* __restrict__ bsum) {
    __shared__ int tmp[256];
    int i = blockIdx.x * 256 + threadIdx.x;
    int v = (i < N_NODES) ? degi[i] : 0;
    tmp[threadIdx.x] = v;
    __syncthreads();
    for (int o = 1; o < 256; o <<= 1) {
        int t = (threadIdx.x >= o) ? tmp[threadIdx.x - o] : 0;
        __syncthreads();
        tmp[threadIdx.x] += t;
        __syncthreads();
    }
    if (i < N_NODES) cursor[i] = tmp[threadIdx.x] - v;
    if (threadIdx.x == 255) bsum[blockIdx.x] = tmp[255];
}

__global__ void __launch_bounds__(512) s14_scan2(int* bsum) {
    __shared__ int tmp[512];
    int t = threadIdx.x;
    int v = (t < NBLK_SCAN) ? bsum[t] : 0;
    tmp[t] = v;
    __syncthreads();
    for (int o = 1; o < 512; o <<= 1) {
        int a = (t >= o) ? tmp[t - o] : 0;
        __syncthreads();
        tmp[t] += a;
        __syncthreads();
    }
    if (t < NBLK_SCAN) bsum[t] = tmp[t] - v;
}

__global__ void __launch_bounds__(256) s14_scan3_dis(int* cursor, const int* __restrict__ bsum,
                                                     const int* __restrict__ degi, float* dis,
                                                     const int* __restrict__ batch, float* cnts,
                                                     const int* __restrict__ fl) {
    int wide = fl[1];
    int i = blockIdx.x * 256 + threadIdx.x;
    if (i < N_NODES) {
        cursor[i] += bsum[blockIdx.x];
        dis[i] = rsqrtf((float)degi[i] + 1.0f);
        unsigned g = (unsigned)ld_batch(batch, i, wide);
        if (g < N_GRAPH) atomicAdd(&cnts[g], 1.0f);
    }
}

__global__ void s14_csrfill(const int* __restrict__ edge, int* cursor,
                            int* __restrict__ csr_src, const int* __restrict__ fl) {
    int wide = fl[0];
    int e = blockIdx.x * blockDim.x + threadIdx.x;
    if (e < N_EDGES) {
        unsigned s = (unsigned)ld_src(edge, e, wide);
        unsigned d = (unsigned)ld_dst(edge, e, wide);
        if (s < N_NODES && d < N_NODES) {
            int slot = atomicAdd(&cursor[d], 1);
            csr_src[slot] = (int)s;
        }
    }
}

// x̃[v*8+c] = bf16(x[v,c]*dis[v])
__global__ void s14_xprep(const void* x, const float* __restrict__ dis,
                          __hip_bfloat16* __restrict__ xt, const int* __restrict__ fl) {
    int fw = fl[3];
    int i = blockIdx.x * blockDim.x + threadIdx.x;
    if (i < N_NODES * 8) {
        int v = i >> 3, c = i & 7;
        float val = (c < F_INN) ? ldf(x, v * F_INN + c, fw) * dis[v] : 0.f;
        xt[i] = __float2bfloat16(val);
    }
}

// layer 1: agg x̃ (8ch), *dis[v], @W1+b1, BN stats
__global__ void __launch_bounds__(256) s14_g7_mm_bn(const __hip_bfloat16* __restrict__ xt,
                                                    const void* W1, const void* b1,
                                                    const float* __restrict__ dis,
                                                    const int* __restrict__ cursor,
                                                    const int* __restrict__ csr,
                                                    float* __restrict__ bufB,
                                                    float* sums, float* sumsq,
                                                    const int* __restrict__ fl) {
    int fw = fl[3], f1d = fl[2];
    __shared__ float w[F_INN][HDIM];
    __shared__ float shs[4][HDIM], shs2[4][HDIM];
    int t = threadIdx.x, lane = t & 63, sub = t >> 6;
    for (int i = t; i < F_INN * HDIM; i += 256) w[i / HDIM][i % HDIM] = ldf(W1, i, fw);
    __syncthreads();
    float bb = ldf(b1, lane, f1d);
    float s1 = 0.f, s2 = 0.f;
    for (int v = blockIdx.x * 4 + sub; v < N_NODES; v += gridDim.x * 4) {
        int end = cursor[v];
        int start = (v == 0) ? 0 : cursor[v - 1];
        float aggc = (lane < 8) ? b2f(xt[v * 8 + lane]) : 0.f;
        int j = start;
        for (; j + 7 < end; j += 8) {
            int e0 = csr[j], e1 = csr[j+1], e2 = csr[j+2], e3 = csr[j+3];
            int e4 = csr[j+4], e5 = csr[j+5], e6 = csr[j+6], e7 = csr[j+7];
            if (lane < 8) {
                float a0 = b2f(xt[e0*8+lane]), a1 = b2f(xt[e1*8+lane]);
                float a2 = b2f(xt[e2*8+lane]), a3 = b2f(xt[e3*8+lane]);
                float a4 = b2f(xt[e4*8+lane]), a5 = b2f(xt[e5*8+lane]);
                float a6 = b2f(xt[e6*8+lane]), a7 = b2f(xt[e7*8+lane]);
                aggc += ((a0+a1)+(a2+a3)) + ((a4+a5)+(a6+a7));
            }
        }
        for (; j < end; j++) {
            int s = csr[j];
            if (lane < 8) aggc += b2f(xt[s * 8 + lane]);
        }
        aggc *= dis[v];
        float acc = bb;
#pragma unroll
        for (int c = 0; c < F_INN; c++) acc += __shfl(aggc, c) * w[c][lane];
        bufB[v * HDIM + lane] = acc;
        s1 += acc; s2 += acc * acc;
    }
    shs[sub][lane] = s1; shs2[sub][lane] = s2;
    __syncthreads();
    if (sub == 0) {
        float ts  = shs[0][lane] + shs[1][lane] + shs[2][lane] + shs[3][lane];
        float ts2 = shs2[0][lane] + shs2[1][lane] + shs2[2][lane] + shs2[3][lane];
        atomicAdd(&sums[lane], ts);
        atomicAdd(&sumsq[lane], ts2);
    }
}

__global__ void s14_bn_final(float* sums, float* sumsq, const void* gamma, const void* beta,
                             float* scale, float* shift, const int* __restrict__ fl) {
    int f1d = fl[2];
    int j = threadIdx.x;
    float mean = sums[j] / (float)N_NODES;
    float var  = sumsq[j] / (float)N_NODES - mean * mean;
    float sc = ldf(gamma, j, f1d) * rsqrtf(var + EPSF);
    scale[j] = sc;
    shift[j] = ldf(beta, j, f1d) - mean * sc;
    sums[j] = 0.f; sumsq[j] = 0.f;
}

// streaming prep+matmul: yt[v] = bf16( (relu(bufB[v]*sc+sh)*dis[v]) @ W )
__global__ void __launch_bounds__(256) s14_prep_mm(const float* __restrict__ bufB,
                                                   const void* W,
                                                   const float* __restrict__ scale,
                                                   const float* __restrict__ shift,
                                                   const float* __restrict__ dis,
                                                   __hip_bfloat16* __restrict__ yt,
                                                   const int* __restrict__ fl) {
    int fw = fl[3];
    __shared__ float w[HDIM][HDIM];
    __shared__ float rows[4][HDIM];     // wave-private
    int t = threadIdx.x, lane = t & 63, sub = t >> 6;
    for (int i = t; i < HDIM * HDIM; i += 256) w[i / HDIM][i % HDIM] = ldf(W, i, fw);
    __syncthreads();
    float sc = scale[lane], sh = shift[lane];
    for (int v = blockIdx.x * 4 + sub; v < N_NODES; v += gridDim.x * 4) {
        float r = fmaxf(bufB[v * HDIM + lane] * sc + sh, 0.f) * dis[v];
        rows[sub][lane] = r;
        float acc = 0.f;
#pragma unroll
        for (int k = 0; k < HDIM; k++) acc += rows[sub][k] * w[k][lane];
        yt[v * HDIM + lane] = __float2bfloat16(acc);
    }
}

// pure gather (paired edges): val = dis[v]*(yt[v]+Σ yt[s]) + b ; bufB + BN stats
__global__ void __launch_bounds__(256) s14_gather_bn(const __hip_bfloat16* __restrict__ yt,
                                                     const void* b,
                                                     const float* __restrict__ dis,
                                                     const int* __restrict__ cursor,
                                                     const int* __restrict__ csr,
                                                     float* __restrict__ bufB,
                                                     float* sums, float* sumsq,
                                                     const int* __restrict__ fl) {
    int f1d = fl[2];
    __shared__ float shs[4][HDIM], shs2[4][HDIM];
    int t = threadIdx.x, lane = t & 63, sub = t >> 6;
    int m = lane & 31, half = lane >> 5;
    const unsigned* ytu = (const unsigned*)yt;   // one uint = channels (2m, 2m+1)
    float b0 = ldf(b, 2 * m, f1d), b1v = ldf(b, 2 * m + 1, f1d);
    float s10 = 0.f, s20 = 0.f, s11 = 0.f, s21 = 0.f;
    for (int v = blockIdx.x * 4 + sub; v < N_NODES; v += gridDim.x * 4) {
        int end = cursor[v];
        int start = (v == 0) ? 0 : cursor[v - 1];
        float a0 = 0.f, a1 = 0.f;
        if (half == 0) {                     // self term once
            unsigned u = ytu[(size_t)v * 32 + m];
            a0 += u_lo(u); a1 += u_hi(u);
        }
        int j = start;
        for (; j + 7 < end; j += 8) {        // 8 edges: 4 per half
            int sA0 = csr[j],   sB0 = csr[j+1];
            int sA1 = csr[j+2], sB1 = csr[j+3];
            int sA2 = csr[j+4], sB2 = csr[j+5];
            int sA3 = csr[j+6], sB3 = csr[j+7];
            int e0 = half ? sB0 : sA0;
            int e1 = half ? sB1 : sA1;
            int e2 = half ? sB2 : sA2;
            int e3 = half ? sB3 : sA3;
            unsigned u0 = ytu[(size_t)e0 * 32 + m];
            unsigned u1 = ytu[(size_t)e1 * 32 + m];
            unsigned u2 = ytu[(size_t)e2 * 32 + m];
            unsigned u3 = ytu[(size_t)e3 * 32 + m];
            a0 += (u_lo(u0) + u_lo(u1)) + (u_lo(u2) + u_lo(u3));
            a1 += (u_hi(u0) + u_hi(u1)) + (u_hi(u2) + u_hi(u3));
        }
        for (; j + 1 < end; j += 2) {        // 2 edges: 1 per half
            int sA = csr[j], sB = csr[j+1];
            int e = half ? sB : sA;
            unsigned u = ytu[(size_t)e * 32 + m];
            a0 += u_lo(u); a1 += u_hi(u);
        }
        if (j < end && half == 0) {          // last single edge
            unsigned u = ytu[(size_t)csr[j] * 32 + m];
            a0 += u_lo(u); a1 += u_hi(u);
        }
        a0 += __shfl(a0, lane ^ 32);         // combine halves
        a1 += __shfl(a1, lane ^ 32);
        if (half == 0) {
            float dv = dis[v];
            float v0 = a0 * dv + b0;
            float v1 = a1 * dv + b1v;
            float2* dst = (float2*)&bufB[v * HDIM + 2 * m];
            *dst = make_float2(v0, v1);
            s10 += v0; s20 += v0 * v0;
            s11 += v1; s21 += v1 * v1;
        }
    }
    if (half == 0) {
        shs[sub][2*m] = s10;  shs[sub][2*m+1] = s11;
        shs2[sub][2*m] = s20; shs2[sub][2*m+1] = s21;
    }
    __syncthreads();
    if (sub == 0) {
        float ts  = shs[0][lane] + shs[1][lane] + shs[2][lane] + shs[3][lane];
        float ts2 = shs2[0][lane] + shs2[1][lane] + shs2[2][lane] + shs2[3][lane];
        atomicAdd(&sums[lane], ts);
        atomicAdd(&sumsq[lane], ts2);
    }
}

// pure gather + pool for layer 3
__global__ void __launch_bounds__(256) s14_gather_pool(const __hip_bfloat16* __restrict__ yt,
                                                       const void* b3,
                                                       const float* __restrict__ dis,
                                                       const int* __restrict__ cursor,
                                                       const int* __restrict__ csr,
                                                       const int* __restrict__ batch,
                                                       float* __restrict__ poolsum,
                                                       const int* __restrict__ fl) {
    int f1d = fl[2], wide = fl[1];
    int t = threadIdx.x, lane = t & 63, sub = t >> 6;
    int m = lane & 31, half = lane >> 5;
    const unsigned* ytu = (const unsigned*)yt;
    float b0 = ldf(b3, 2 * m, f1d), b1v = ldf(b3, 2 * m + 1, f1d);
    for (int v = blockIdx.x * 4 + sub; v < N_NODES; v += gridDim.x * 4) {
        int end = cursor[v];
        int start = (v == 0) ? 0 : cursor[v - 1];
        float a0 = 0.f, a1 = 0.f;
        if (half == 0) {
            unsigned u = ytu[(size_t)v * 32 + m];
            a0 += u_lo(u); a1 += u_hi(u);
        }
        int j = start;
        for (; j + 7 < end; j += 8) {
            int sA0 = csr[j],   sB0 = csr[j+1];
            int sA1 = csr[j+2], sB1 = csr[j+3];
            int sA2 = csr[j+4], sB2 = csr[j+5];
            int sA3 = csr[j+6], sB3 = csr[j+7];
            int e0 = half ? sB0 : sA0;
            int e1 = half ? sB1 : sA1;
            int e2 = half ? sB2 : sA2;
            int e3 = half ? sB3 : sA3;
            unsigned u0 = ytu[(size_t)e0 * 32 + m];
            unsigned u1 = ytu[(size_t)e1 * 32 + m];
            unsigned u2 = ytu[(size_t)e2 * 32 + m];
            unsigned u3 = ytu[(size_t)e3 * 32 + m];
            a0 += (u_lo(u0) + u_lo(u1)) + (u_lo(u2) + u_lo(u3));
            a1 += (u_hi(u0) + u_hi(u1)) + (u_hi(u2) + u_hi(u3));
        }
        for (; j + 1 < end; j += 2) {
            int sA = csr[j], sB = csr[j+1];
            int e = half ? sB : sA;
            unsigned u = ytu[(size_t)e * 32 + m];
            a0 += u_lo(u); a1 += u_hi(u);
        }
        if (j < end && half == 0) {
            unsigned u = ytu[(size_t)csr[j] * 32 + m];
            a0 += u_lo(u); a1 += u_hi(u);
        }
        a0 += __shfl(a0, lane ^ 32);
        a1 += __shfl(a1, lane ^ 32);
        if (half == 0) {
            float dv = dis[v];
            unsigned g = (unsigned)ld_batch(batch, v, wide);
            if (g < N_GRAPH) {
                atomicAdd(&poolsum[g * HDIM + 2*m],     a0 * dv + b0);
                atomicAdd(&poolsum[g * HDIM + 2*m + 1], a1 * dv + b1v);
            }
        }
    }
}

__global__ void __launch_bounds__(64) s14_head(const float* __restrict__ poolsum,
                                               const float* __restrict__ cnts,
                                               const void* gfeat, const void* Wg, const void* bg,
                                               const void* Wp1, const void* bp1,
                                               const void* Wp2, const void* bp2,
                                               float* __restrict__ out,
                                               const int* __restrict__ fl) {
    int f1d = fl[2], fw = fl[3];
    int g = blockIdx.x, t = threadIdx.x;
    __shared__ float comb[HDIM + HDIM / 2];
    __shared__ float hid[HDIM];
    float cnt = fmaxf(cnts[g], 1.0f);
    comb[t] = poolsum[g * HDIM + t] / cnt;
    if (t < HDIM / 2) {
        float a = ldf(bg, t, f1d);
#pragma unroll
        for (int k = 0; k < GFEAT; k++)
            a += ldf(gfeat, g * GFEAT + k, fw) * ldf(Wg, k * (HDIM / 2) + t, fw);
        comb[HDIM + t] = fmaxf(a, 0.f);
    }
    __syncthreads();
    float a = ldf(bp1, t, f1d);
    for (int k = 0; k < HDIM + HDIM / 2; k++) a += comb[k] * ldf(Wp1, k * HDIM + t, fw);
    hid[t] = fmaxf(a, 0.f);
    __syncthreads();
    if (t < T_OUT) {
        float o = ldf(bp2, t, f1d);
#pragma unroll
        for (int k = 0; k < HDIM; k++) o += hid[k] * ldf(Wp2, k * T_OUT + t, fw);
        out[g * T_OUT + t] = o;
    }
}

extern "C" __attribute__((visibility("default")))
void kernel_launch(void* const* d_in, const int* in_sizes, int n_in,
                   void* d_out, int out_size, void* d_ws, size_t ws_size,
                   hipStream_t stream) {
    static const int exp_sizes[20] = {700000, 10000, 448, 64, 4096, 64, 4096, 64,
                                      64, 64, 64, 64, 320, 32, 6144, 64, 320, 5,
                                      2400000, 100000};
    bool ok = (n_in == 20) && (out_size == N_GRAPH * T_OUT);
    if (ok) for (int i = 0; i < 20; i++) ok = ok && (in_sizes[i] == exp_sizes[i]);
    if (!ok) {
        s14_fill<<<(out_size + 255) / 256, 256, 0, stream>>>((float*)d_out, out_size, 900.0f);
        return;
    }

    const void* x      = d_in[0];
    const void* gfeat  = d_in[1];
    const void* W1     = d_in[2];
    const void* b1     = d_in[3];
    const void* W2     = d_in[4];
    const void* b2     = d_in[5];
    const void* W3     = d_in[6];
    const void* b3     = d_in[7];
    const void* gamma1 = d_in[8];
    const void* beta1  = d_in[9];
    const void* gamma2 = d_in[10];
    const void* beta2  = d_in[11];
    const void* Wg     = d_in[12];
    const void* bg     = d_in[13];
    const void* Wp1    = d_in[14];
    const void* bp1    = d_in[15];
    const void* Wp2    = d_in[16];
    const void* bp2    = d_in[17];
    const int* edge  = (const int*)d_in[18];
    const int* batch = (const int*)d_in[19];

    // workspace layout (4-byte words)
    int*   flags   = (int*)d_ws;                        // 16
    int*   degi    = flags + 16;                        // N
    float* dis     = (float*)(degi + N_NODES);          // N
    float* cnts    = dis + N_NODES;                     // G
    float* sums    = cnts + N_GRAPH;                    // H
    float* sumsq   = sums + HDIM;                       // H
    float* scale   = sumsq + HDIM;                      // H
    float* shift   = scale + HDIM;                      // H
    float* poolsum = shift + HDIM;                      // G*H
    int*   cursor  = (int*)(poolsum + N_GRAPH * HDIM);  // N
    int*   bsum    = cursor + N_NODES;                  // 512
    int*   csr_src = bsum + 512;                        // E
    __hip_bfloat16* xt = (__hip_bfloat16*)(csr_src + N_EDGES);  // N*8 bf16
    __hip_bfloat16* yt = xt + (size_t)N_NODES * 8;              // N*64 bf16
    float* bufB    = (float*)(yt + (size_t)N_NODES * HDIM);     // N*H fp32

    const size_t need = (size_t)(16 + 3 * N_NODES + N_GRAPH + 4 * HDIM + N_GRAPH * HDIM
                                 + 512 + N_EDGES + 4 * N_NODES + 32 * N_NODES
                                 + 64 * (size_t)N_NODES) * 4;
    if (ws_size < need) {
        s14_fill<<<(out_size + 255) / 256, 256, 0, stream>>>((float*)d_out, out_size, 500.0f);
        return;
    }

    s14_probe<<<1, 256, 0, stream>>>(edge, batch, (const unsigned*)gamma1,
                                     (const unsigned short*)x, (const unsigned short*)W1,
                                     (const unsigned short*)W2, flags);

    int zcount = 2 * N_NODES + N_GRAPH + 4 * HDIM + N_GRAPH * HDIM;
    s14_zero<<<(zcount + 255) / 256, 256, 0, stream>>>(degi, zcount);

    s14_deg<<<(N_EDGES + 255) / 256, 256, 0, stream>>>(edge, degi, flags);
    s14_scan1<<<NBLK_SCAN, 256, 0, stream>>>(degi, cursor, bsum);
    s14_scan2<<<1, 512, 0, stream>>>(bsum);
    s14_scan3_dis<<<NBLK_SCAN, 256, 0, stream>>>(cursor, bsum, degi, dis, batch, cnts, flags);
    s14_csrfill<<<(N_EDGES + 255) / 256, 256, 0, stream>>>(edge, cursor, csr_src, flags);

    // layer 1
    s14_xprep<<<(N_NODES * 8 + 255) / 256, 256, 0, stream>>>(x, dis, xt, flags);
    s14_g7_mm_bn<<<2048, 256, 0, stream>>>(xt, W1, b1, dis, cursor, csr_src,
                                           bufB, sums, sumsq, flags);
    s14_bn_final<<<1, 64, 0, stream>>>(sums, sumsq, gamma1, beta1, scale, shift, flags);

    // layer 2: streaming matmul-prep, then pure gather
    s14_prep_mm<<<2048, 256, 0, stream>>>(bufB, W2, scale, shift, dis, yt, flags);
    s14_gather_bn<<<2048, 256, 0, stream>>>(yt, b2, dis, cursor, csr_src,
                                            bufB, sums, sumsq, flags);
    s14_bn_final<<<1, 64, 0, stream>>>(sums, sumsq, gamma2, beta2, scale, shift, flags);

    // layer 3
    s14_prep_mm<<<2048, 256, 0, stream>>>(bufB, W3, scale, shift, dis, yt, flags);
    s14_gather_pool<<<2048, 256, 0, stream>>>(yt, b3, dis, cursor, csr_src,
                                              batch, poolsum, flags);

    // head
    s14_head<<<N_GRAPH, 64, 0, stream>>>(poolsum, cnts, gfeat, Wg, bg, Wp1, bp1, Wp2, bp2,
                                         (float*)d_out, flags);
}